// Round 3
// baseline (298.393 us; speedup 1.0000x reference)
//
#include <hip/hip_runtime.h>

// Winograd F(4x4,3x3), fp32. x:[16,64,130,130] w:[64,64,3,3] -> y:[16,64,128,128]
// filter -> input transform (V) -> per-ab GEMM (M, U via scalar loads) -> output transform.
// ws layout: U[36][64][64] | V[36][64][Pchunk] | M[36][64][Pchunk]

__constant__ float c_AT[24] = {   // c_AT[i*4+u] = A_T[u][i] (columns of A_T)
  1.f, 0.f, 0.f, 0.f,
  1.f, 1.f, 1.f, 1.f,
  1.f,-1.f, 1.f,-1.f,
  1.f, 2.f, 4.f, 8.f,
  1.f,-2.f, 4.f,-8.f,
  0.f, 0.f, 0.f, 1.f
};

__device__ __forceinline__ void gl2lds16(const float* g, float* l) {
  __builtin_amdgcn_global_load_lds((const __attribute__((address_space(1))) void*)g,
                                   (__attribute__((address_space(3))) void*)l, 16, 0, 0);
}

// ---------------- K0: filter transform U = G w G^T, layout [ab][c][k] ----------------
__global__ __launch_bounds__(256) void k_filter(const float* __restrict__ w,
                                                float* __restrict__ U) {
  int g = blockIdx.x * 256 + threadIdx.x;     // 0..4095
  int k = g & 63;
  int c = g >> 6;
  const float* wp = w + (size_t)(k * 64 + c) * 9;
  float w00 = wp[0], w01 = wp[1], w02 = wp[2];
  float w10 = wp[3], w11 = wp[4], w12 = wp[5];
  float w20 = wp[6], w21 = wp[7], w22 = wp[8];
  const float G[6][3] = {
    {0.25f, 0.f, 0.f},
    {-1.f/6.f, -1.f/6.f, -1.f/6.f},
    {-1.f/6.f,  1.f/6.f, -1.f/6.f},
    {1.f/24.f,  1.f/12.f, 1.f/6.f},
    {1.f/24.f, -1.f/12.f, 1.f/6.f},
    {0.f, 0.f, 1.f}
  };
  float t[6][3];
#pragma unroll
  for (int a = 0; a < 6; ++a) {
    t[a][0] = G[a][0]*w00 + G[a][1]*w10 + G[a][2]*w20;
    t[a][1] = G[a][0]*w01 + G[a][1]*w11 + G[a][2]*w21;
    t[a][2] = G[a][0]*w02 + G[a][1]*w12 + G[a][2]*w22;
  }
#pragma unroll
  for (int a = 0; a < 6; ++a) {
#pragma unroll
    for (int b = 0; b < 6; ++b) {
      float u = G[b][0]*t[a][0] + G[b][1]*t[a][1] + G[b][2]*t[a][2];
      U[(size_t)(a*6+b)*4096 + c*64 + k] = u;
    }
  }
}

// ---------------- K1: input transform V = B^T d B, layout [ab][c][p] ----------------
__global__ __launch_bounds__(256) void k_input(const float* __restrict__ x,
                                               float* __restrict__ V,
                                               int n0, int Pchunk) {
  __shared__ float Ls[34*134];
  const int tid  = threadIdx.x;
  const int bi   = blockIdx.x;
  const int band = bi & 3;
  const int c    = (bi >> 2) & 63;
  const int nl   = bi >> 8;
  const float* xp = x + (size_t)((n0 + nl) * 64 + c) * (130*130) + band * 32 * 130;
  for (int idx = tid; idx < 34*65; idx += 256) {
    int r  = idx / 65;
    int c2 = idx - r * 65;
    *(float2*)&Ls[r*134 + c2*2] = *(const float2*)(xp + r*130 + c2*2);
  }
  __syncthreads();
  const int tyl = tid >> 5;
  const int tx  = tid & 31;
  const int ty  = band * 8 + tyl;
  const int p   = (nl * 32 + ty) * 32 + tx;
  const float* bl = &Ls[(tyl*4)*134 + tx*4];
  float t1[6][6];
#pragma unroll
  for (int j = 0; j < 6; ++j) {
    float d0 = bl[0*134+j], d1 = bl[1*134+j], d2 = bl[2*134+j];
    float d3 = bl[3*134+j], d4 = bl[4*134+j], d5 = bl[5*134+j];
    t1[0][j] =  4.f*d0 - 5.f*d2 + d4;
    t1[1][j] = -4.f*d1 - 4.f*d2 + d3 + d4;
    t1[2][j] =  4.f*d1 - 4.f*d2 - d3 + d4;
    t1[3][j] = -2.f*d1 -     d2 + 2.f*d3 + d4;
    t1[4][j] =  2.f*d1 -     d2 - 2.f*d3 + d4;
    t1[5][j] =  4.f*d1 - 5.f*d3 + d5;
  }
  float* vb = V + (size_t)c * Pchunk + p;
  const size_t abs_ = (size_t)64 * Pchunk;
#pragma unroll
  for (int a = 0; a < 6; ++a) {
    float s0=t1[a][0], s1=t1[a][1], s2=t1[a][2], s3=t1[a][3], s4=t1[a][4], s5=t1[a][5];
    float v0 =  4.f*s0 - 5.f*s2 + s4;
    float v1 = -4.f*s1 - 4.f*s2 + s3 + s4;
    float v2 =  4.f*s1 - 4.f*s2 - s3 + s4;
    float v3 = -2.f*s1 -     s2 + 2.f*s3 + s4;
    float v4 =  2.f*s1 -     s2 - 2.f*s3 + s4;
    float v5 =  4.f*s1 - 5.f*s3 + s5;
    vb[(size_t)(a*6+0)*abs_] = v0;
    vb[(size_t)(a*6+1)*abs_] = v1;
    vb[(size_t)(a*6+2)*abs_] = v2;
    vb[(size_t)(a*6+3)*abs_] = v3;
    vb[(size_t)(a*6+4)*abs_] = v4;
    vb[(size_t)(a*6+5)*abs_] = v5;
  }
}

// ---------------- K2: per-ab GEMM  M[ab][k][p] = sum_c U[ab][c][k] * V[ab][c][p] ----------------
// block = 512 p x 64 k for one ab. wave w owns k-group w*16 (uniform -> U via s_load, scalar pipe).
// thread: 8 p (2x ds_read_b128) x 16 k (SGPRs) = 128 FMA per c. V double-buffered in 16-c chunks.
__global__ __launch_bounds__(256, 2) void k_gemm3(const float* __restrict__ V,
                                                  const float* __restrict__ U,
                                                  float* __restrict__ M,
                                                  int Pchunk, int nPB) {
  __shared__ float Vs[2][16][512];   // 64 KB
  const int tid  = threadIdx.x;
  const int lane = tid & 63;
  const int wv   = tid >> 6;
  const unsigned bx = blockIdx.x;
  const int ab = bx / (unsigned)nPB;
  const int pb = bx - ab * nPB;
  const int p0 = pb * 512;
  const float* Vab = V + (size_t)ab * 64 * Pchunk + p0;
  const float* Uab = U + (size_t)ab * 4096;                 // [c][k]
  const int k0 = __builtin_amdgcn_readfirstlane(wv * 16);   // force wave-uniform -> s_load for U

  // stage chunk cc into buf: 16 rows x 512 floats; 32 half-rows / 4 waves = 8 per wave
#define STAGE(cc, buf)                                                        \
  {                                                                           \
    _Pragma("unroll")                                                         \
    for (int i = 0; i < 8; ++i) {                                             \
      int h = wv * 8 + i;                                                     \
      int r = h >> 1, hf = h & 1;                                             \
      gl2lds16(Vab + (size_t)((cc)*16 + r) * Pchunk + hf*256 + lane*4,        \
               &Vs[(buf)][r][hf*256]);                                        \
    }                                                                         \
  }

  float acc[16][8];
#pragma unroll
  for (int kk = 0; kk < 16; ++kk)
#pragma unroll
    for (int pp = 0; pp < 8; ++pp) acc[kk][pp] = 0.f;

  STAGE(0, 0);
  for (int cc = 0; cc < 4; ++cc) {
    __syncthreads();                       // chunk cc resident (drains prefetch vmcnt)
    if (cc < 3) STAGE(cc + 1, (cc + 1) & 1);
    const float* vsb = &Vs[cc & 1][0][0];
#pragma unroll
    for (int c = 0; c < 16; ++c) {
      const float* uc = Uab + (size_t)(cc * 16 + c) * 64 + k0;   // uniform -> s_load_dwordx16
      float4 va = *(const float4*)(vsb + c * 512 + lane * 4);
      float4 vb = *(const float4*)(vsb + c * 512 + 256 + lane * 4);
      float vv[8] = {va.x, va.y, va.z, va.w, vb.x, vb.y, vb.z, vb.w};
#pragma unroll
      for (int kk = 0; kk < 16; ++kk) {
        float u = uc[kk];
#pragma unroll
        for (int pp = 0; pp < 8; ++pp) acc[kk][pp] += u * vv[pp];
      }
    }
  }
#undef STAGE

  float* mb = M + ((size_t)ab * 64 + k0) * Pchunk + p0;
#pragma unroll
  for (int kk = 0; kk < 16; ++kk) {
    *(float4*)(mb + (size_t)kk * Pchunk + lane * 4) =
        make_float4(acc[kk][0], acc[kk][1], acc[kk][2], acc[kk][3]);
    *(float4*)(mb + (size_t)kk * Pchunk + 256 + lane * 4) =
        make_float4(acc[kk][4], acc[kk][5], acc[kk][6], acc[kk][7]);
  }
}

// ---------------- K3: output transform Y = A_T M A, 4 p per thread (float4) ----------------
__global__ __launch_bounds__(256) void k_out2(const float* __restrict__ M,
                                              float* __restrict__ out,
                                              int n0, int Pchunk, int bpk) {
  const unsigned bx = blockIdx.x;
  const int k    = bx / (unsigned)bpk;
  const int pblk = bx - k * bpk;
  const int p    = pblk * 1024 + threadIdx.x * 4;
  const int nl = p >> 10;
  const int ty = (p >> 5) & 31;
  const int tx = p & 31;

  const float* mp = M + (size_t)k * Pchunk + p;
  const size_t abstride = (size_t)64 * Pchunk;

  float Y[4][4][4];   // [u][v][pvec]
#pragma unroll
  for (int u = 0; u < 4; ++u)
#pragma unroll
    for (int v = 0; v < 4; ++v)
#pragma unroll
      for (int q = 0; q < 4; ++q) Y[u][v][q] = 0.f;

#pragma unroll
  for (int i = 0; i < 6; ++i) {
    float R[4][4];
#pragma unroll
    for (int v = 0; v < 4; ++v)
#pragma unroll
      for (int q = 0; q < 4; ++q) R[v][q] = 0.f;
#pragma unroll
    for (int j = 0; j < 6; ++j) {
      float4 m4 = *(const float4*)(mp + (size_t)(i * 6 + j) * abstride);
      float mm[4] = {m4.x, m4.y, m4.z, m4.w};
#pragma unroll
      for (int v = 0; v < 4; ++v) {
        float av = c_AT[j * 4 + v];
#pragma unroll
        for (int q = 0; q < 4; ++q) R[v][q] += av * mm[q];
      }
    }
#pragma unroll
    for (int u = 0; u < 4; ++u) {
      float au = c_AT[i * 4 + u];
#pragma unroll
      for (int v = 0; v < 4; ++v)
#pragma unroll
        for (int q = 0; q < 4; ++q) Y[u][v][q] += au * R[v][q];
    }
  }

  float* ob = out + ((size_t)((n0 + nl) * 64 + k) * 128 + ty * 4) * 128 + tx * 4;
#pragma unroll
  for (int u = 0; u < 4; ++u)
    *(float4*)(ob + (size_t)u * 128) = make_float4(Y[u][0][0], Y[u][1][0], Y[u][2][0], Y[u][3][0])
    , *(float4*)(ob + (size_t)u * 128 + 4)  = make_float4(Y[u][0][1], Y[u][1][1], Y[u][2][1], Y[u][3][1])
    , *(float4*)(ob + (size_t)u * 128 + 8)  = make_float4(Y[u][0][2], Y[u][1][2], Y[u][2][2], Y[u][3][2])
    , *(float4*)(ob + (size_t)u * 128 + 12) = make_float4(Y[u][0][3], Y[u][1][3], Y[u][2][3], Y[u][3][3]);
}

extern "C" void kernel_launch(void* const* d_in, const int* in_sizes, int n_in,
                              void* d_out, int out_size, void* d_ws, size_t ws_size,
                              hipStream_t stream) {
  const float* x = (const float*)d_in[0];
  const float* w = (const float*)d_in[1];
  float* out = (float*)d_out;
  float* U = (float*)d_ws;
  const size_t U_bytes = 36ull * 64 * 64 * 4;        // 589824
  const size_t per_n = 2ull * 36 * 1024 * 64 * 4;    // V + M per image
  size_t avail = ws_size > U_bytes ? ws_size - U_bytes : 0;
  int chunk = (int)(avail / per_n);
  if (chunk < 1) return;
  if (chunk > 8) chunk = 8;                          // keep V+M inside 256 MB L3

  k_filter<<<16, 256, 0, stream>>>(w, U);
  for (int n0 = 0; n0 < 16; n0 += chunk) {
    int cn = (16 - n0) < chunk ? (16 - n0) : chunk;
    int Pchunk = cn * 1024;
    float* V = (float*)((char*)d_ws + U_bytes);
    float* M = V + (size_t)36 * 64 * Pchunk;
    int nPBg = cn * 2;                               // 512-p tiles per ab
    k_input<<<cn*256,   256, 0, stream>>>(x, V, n0, Pchunk);
    k_gemm3<<<36*nPBg,  256, 0, stream>>>(V, U, M, Pchunk, nPBg);
    k_out2 <<<64*cn,    256, 0, stream>>>(M, out, n0, Pchunk, cn);
  }
}